// Round 4
// baseline (607.235 us; speedup 1.0000x reference)
//
#include <hip/hip_runtime.h>
#include <hip/hip_bf16.h>
#include <math.h>

typedef __attribute__((ext_vector_type(8))) short bf16x8;
typedef __attribute__((ext_vector_type(4))) float f32x4;
typedef __attribute__((ext_vector_type(4))) unsigned int u32x4;

#define NP 16384
#define HWFULL 65536

__device__ __forceinline__ unsigned short f2bf(float f){
    union { float f; unsigned int u; } v; v.f = f;
    unsigned int u = v.u;
    u += 0x7fffu + ((u >> 16) & 1u);
    return (unsigned short)(u >> 16);
}
__device__ __forceinline__ float bf2f(unsigned short h){
    union { unsigned int u; float f; } v; v.u = ((unsigned int)h) << 16;
    return v.f;
}
// HW packed bf16 convert (RNE, identical rounding to f2bf): 1 instr vs ~10
__device__ __forceinline__ unsigned int pk2(float a, float b){
    unsigned int r;
    asm("v_cvt_pk_bf16_f32 %0, %1, %2" : "=v"(r) : "v"(a), "v"(b));
    return r;
}

// ---- K0: fp32 -> bf16 weight conversion ----
__global__ void k_convert(const float* __restrict__ s, unsigned short* __restrict__ d, int n){
    int i = blockIdx.x * 256 + threadIdx.x;
    if (i < n) d[i] = f2bf(s[i]);
}

// ---- K1: qkv 1x1 conv (bf16 MFMA GEMM) fused with 2x2 maxpool ----
// v7: SAME tile (192oc x 128pos), SAME staging pattern, but 384-thread / 6-wave
// blocks with acc[2][8] per wave (64 AGPR vs 96). ~142 unified regs -> 3 waves/SIMD
// (12 waves/CU) instead of 2: clean +50% occupancy test vs the v4 structure.
// grid (512, 4): bx -> (y2 = bx>>2, x2blk = bx&3); by = b
__global__ __launch_bounds__(384, 3)
void k_qkvpool(const float* __restrict__ x, const unsigned short* __restrict__ Wbf,
               unsigned short* __restrict__ qkvp){
    __shared__ unsigned short Bl[128*200];  // [pos][K=192 + pad8] bf16, persistent
    __shared__ unsigned short Ep[192*36];   // pooled epilogue buffer
    int tid = threadIdx.x;
    int lane = tid & 63, wv = tid >> 6;     // wv in 0..5
    int n16 = lane & 15, quad = lane >> 4;
    int bx = blockIdx.x;
    int y2 = bx >> 2, x2blk = bx & 3;
    int b = blockIdx.y;

    // ---- stage B: transpose-gather x[ic][pos] -> Bl[pos][ic], fp32->bf16, full K ----
    // 3072 granule-loads over 384 threads = 8 iters
    #pragma unroll 4
    for (int j=0;j<8;j++){
        int idx = tid + j*384;
        int g = idx >> 7, w = idx & 127;       // g: ic granule of 8; w: 0..63 row y, 64..127 row y+1
        int y = y2*2 + (w >> 6);
        int xc = x2blk*64 + (w & 63);
        const float* xp = x + (size_t)(b*192 + g*8) * HWFULL + y*256 + xc;
        float v0 = xp[0];
        float v1 = xp[(size_t)1*HWFULL];
        float v2 = xp[(size_t)2*HWFULL];
        float v3 = xp[(size_t)3*HWFULL];
        float v4 = xp[(size_t)4*HWFULL];
        float v5 = xp[(size_t)5*HWFULL];
        float v6 = xp[(size_t)6*HWFULL];
        float v7 = xp[(size_t)7*HWFULL];
        u32x4 pk;
        pk.x = pk2(v0,v1); pk.y = pk2(v2,v3); pk.z = pk2(v4,v5); pk.w = pk2(v6,v7);
        *(u32x4*)&Bl[w*200 + g*8] = pk;
    }
    // preload A fragments for (ocblk=0, it=0) — independent of LDS
    bf16x8 afc[2], afn[2];
    #pragma unroll
    for (int j=0;j<2;j++)
        afc[j] = *(const bf16x8*)(Wbf + (size_t)(((wv*2+j)*16 + n16)*192 + quad*8));
    __syncthreads();

    for (int ocblk=0; ocblk<3; ocblk++){
        f32x4 acc[2][8];
        #pragma unroll
        for (int j=0;j<2;j++)
          #pragma unroll
          for (int s=0;s<8;s++)
            acc[j][s] = (f32x4){0.f,0.f,0.f,0.f};

        #pragma unroll 1
        for (int it=0; it<6; it++){
            int nocb = (it==5) ? ocblk+1 : ocblk;
            int nit  = (it==5) ? 0 : it+1;
            if (nocb < 3){
                #pragma unroll
                for (int j=0;j<2;j++)
                    afn[j] = *(const bf16x8*)(Wbf +
                        (size_t)((nocb*192 + (wv*2+j)*16 + n16)*192 + nit*32 + quad*8));
            }
            int bko = it*32 + quad*8;
            bf16x8 bfr[8];
            #pragma unroll
            for (int s=0;s<8;s++) bfr[s] = *(const bf16x8*)&Bl[(s*16 + n16)*200 + bko];
            #pragma unroll
            for (int j=0;j<2;j++)
              #pragma unroll
              for (int s=0;s<8;s++)
                acc[j][s] = __builtin_amdgcn_mfma_f32_16x16x32_bf16(afc[j], bfr[s], acc[j][s], 0,0,0);
            #pragma unroll
            for (int j=0;j<2;j++) afc[j] = afn[j];
        }
        __syncthreads();   // prev ocblk's cooperative-store reads of Ep done
        // ---- epilogue: 2x2 maxpool into LDS (strip sp & sp+4 = rows y,y+1; lane^1 = x,x+1)
        #pragma unroll
        for (int j=0;j<2;j++){
            int ocr = (wv*2+j)*16 + quad*4;
            #pragma unroll
            for (int sp=0;sp<4;sp++){
                #pragma unroll
                for (int r=0;r<4;r++){
                    float v = fmaxf(acc[j][sp][r], acc[j][sp+4][r]);
                    float o = __shfl_xor(v, 1, 64);
                    v = fmaxf(v, o);
                    if ((n16 & 1) == 0)
                        Ep[(ocr + r)*36 + sp*8 + (n16 >> 1)] = f2bf(v);
                }
            }
        }
        __syncthreads();
        // ---- cooperative coalesced store: 192 rows x 32 shorts (64B/row) ----
        // 1536 uint2 over 384 threads = 4 iters
        size_t rowbase = (size_t)(b*576 + ocblk*192)*NP + y2*128 + x2blk*32;
        #pragma unroll
        for (int it2=0; it2<4; it2++){
            int c = tid + it2*384;
            int row = c >> 3, seg = c & 7;
            uint2 vv = *(const uint2*)&Ep[row*36 + seg*4];
            *(uint2*)(qkvp + rowbase + (size_t)row*NP + seg*4) = vv;
        }
    }
}

// ---- K2: depthwise 3x3 SAME conv + per-channel sum-of-squares (q,k only) ----
// v3: bf16 OUTPUT (halves dwout traffic); ssq still from fp32 values.
// grid (8, 576, 4), block 256
__global__ void k_dwconv(const unsigned short* __restrict__ qkvp, const float* __restrict__ dww,
                         unsigned short* __restrict__ dwoutB, float* __restrict__ sumsq){
    __shared__ float sl[18*132];   // [row][gx+2], gx in [-1,128] -> idx 1..130
    int tid = threadIdx.x;
    int y0 = blockIdx.x * 16;
    int ch = blockIdx.y;
    int b  = blockIdx.z;
    const unsigned short* in = qkvp + (size_t)(b*576 + ch) * NP;
    int l = tid & 63, wr = tid >> 6;
    #pragma unroll
    for (int j=0;j<5;j++){
        int row = wr + j*4;
        if (row < 18){
            int gy = y0 - 1 + row;
            float2 v = make_float2(0.f, 0.f);
            if (gy >= 0 && gy < 128){
                unsigned int u = *(const unsigned int*)&in[gy*128 + l*2];
                v.x = bf2f((unsigned short)(u & 0xffffu));
                v.y = bf2f((unsigned short)(u >> 16));
            }
            *(float2*)&sl[row*132 + 2 + l*2] = v;
        }
    }
    if (tid < 18) sl[tid*132 + 1] = 0.f;              // left halo (gx=-1)
    else if (tid < 36) sl[(tid-18)*132 + 130] = 0.f;  // right halo (gx=128)
    float w0 = dww[ch*9+0], w1 = dww[ch*9+1], w2 = dww[ch*9+2];
    float w3 = dww[ch*9+3], w4 = dww[ch*9+4], w5 = dww[ch*9+5];
    float w6 = dww[ch*9+6], w7 = dww[ch*9+7], w8 = dww[ch*9+8];
    __syncthreads();
    unsigned short* outp = dwoutB + (size_t)(b*576 + ch) * NP;
    int col = tid & 127, half = tid >> 7;
    float ssq = 0.f;
    int base = (half*8)*132 + col + 1;   // sl[row][col-1] of first input row
    float r0a=sl[base],     r0b=sl[base+1],   r0c=sl[base+2];
    float r1a=sl[base+132], r1b=sl[base+133], r1c=sl[base+134];
    #pragma unroll
    for (int i=0;i<8;i++){
        const float* r2 = &sl[base + (i+2)*132];
        float r2a=r2[0], r2b=r2[1], r2c=r2[2];
        float a = r0a*w0 + r0b*w1 + r0c*w2
                + r1a*w3 + r1b*w4 + r1c*w5
                + r2a*w6 + r2b*w7 + r2c*w8;
        outp[(y0 + half*8 + i)*128 + col] = f2bf(a);
        ssq += a*a;
        r0a=r1a; r0b=r1b; r0c=r1c;
        r1a=r2a; r1b=r2b; r1c=r2c;
    }
    if (ch < 384){
        #pragma unroll
        for (int off=32; off>0; off>>=1) ssq += __shfl_down(ssq, off, 64);
        if ((tid & 63) == 0) atomicAdd(&sumsq[b*384 + ch], ssq);
    }
}

// ---- K3a: raw attention gram matrix — bf16 input (halved traffic) ----
// grid (32, 6, 4), block 256
__global__ __launch_bounds__(256) void k_attnraw(const unsigned short* __restrict__ dwoutB,
                                                 float* __restrict__ attn){
    __shared__ float sq[128*34];
    __shared__ float sk[128*34];
    int tid = threadIdx.x;
    int n0 = blockIdx.x * 512;
    int h = blockIdx.y, b = blockIdx.z;
    const unsigned short* qb = dwoutB + (size_t)(b*576 + h*32)*NP + n0;
    const unsigned short* kb = dwoutB + (size_t)(b*576 + 192 + h*32)*NP + n0;
    int s = tid >> 6, l = tid & 63;
    int c0 = (l & 7) * 4, d0 = (l >> 3) * 4;
    float acc[4][4];
    #pragma unroll
    for (int i=0;i<4;i++)
      #pragma unroll
      for (int j=0;j<4;j++) acc[i][j] = 0.f;

    for (int slc=0; slc<4; slc++){
        int nb = slc*128;
        __syncthreads();
        #pragma unroll 4
        for (int j=0;j<16;j++){
            int idx = tid + j*256;
            int r = idx >> 7, c = idx & 127;
            sq[c*34 + r] = bf2f(qb[(size_t)r*NP + nb + c]);
            sk[c*34 + r] = bf2f(kb[(size_t)r*NP + nb + c]);
        }
        __syncthreads();
        #pragma unroll 4
        for (int i=0;i<32;i++){
            int n = s*32 + i;
            const float* qp = &sq[n*34];
            const float* kp = &sk[n*34];
            float2 qa = *(const float2*)(qp + c0);
            float2 qc = *(const float2*)(qp + c0 + 2);
            float2 ka = *(const float2*)(kp + d0);
            float2 kc = *(const float2*)(kp + d0 + 2);
            float qv[4] = {qa.x, qa.y, qc.x, qc.y};
            float kv[4] = {ka.x, ka.y, kc.x, kc.y};
            #pragma unroll
            for (int ci=0;ci<4;ci++)
              #pragma unroll
              for (int di=0;di<4;di++)
                acc[ci][di] += qv[ci]*kv[di];
        }
    }
    __syncthreads();
    float* red = sq;   // [s][32][33] partials
    #pragma unroll
    for (int ci=0;ci<4;ci++)
      #pragma unroll
      for (int di=0;di<4;di++)
        red[(s*32 + c0+ci)*33 + d0+di] = acc[ci][di];
    __syncthreads();
    float* ap = attn + (size_t)(b*6+h)*1024;
    #pragma unroll
    for (int j=0;j<4;j++){
        int o = tid + j*256;
        int c = o >> 5, d = o & 31;
        float v = red[(0*32 + c)*33 + d] + red[(1*32 + c)*33 + d]
                + red[(2*32 + c)*33 + d] + red[(3*32 + c)*33 + d];
        atomicAdd(ap + o, v);
    }
}

// ---- K3b: normalize, temperature, 4x top-k masked softmax, combine ----
// v2: fully wave-parallel — 1024 threads, one per (c,d); shfl-reduce rows.
// grid 24, block 1024
__global__ void k_mask_softmax(const float* __restrict__ attn, const float* __restrict__ sumsq,
                               const float* __restrict__ temp,
                               const float* __restrict__ A1, const float* __restrict__ A2,
                               const float* __restrict__ A3, const float* __restrict__ A4,
                               float* __restrict__ comb){
    __shared__ float Am[32][33];
    __shared__ float qn[32], kn[32];
    int t = threadIdx.x;
    int bh = blockIdx.x;
    int b = bh / 6, h = bh % 6;
    if (t < 32) qn[t] = fmaxf(sqrtf(sumsq[b*384 + h*32 + t]), 1e-12f);
    else if (t >= 64 && t < 96) kn[t-64] = fmaxf(sqrtf(sumsq[b*384 + 192 + h*32 + (t-64)]), 1e-12f);
    __syncthreads();
    int c = t >> 5, d = t & 31;
    float tv = temp[h];
    float am = attn[(size_t)bh*1024 + t] * tv / (qn[c]*kn[d]);
    Am[c][d] = am;
    // row max (32-lane subgroups)
    float m = am;
    #pragma unroll
    for (int off=16; off>0; off>>=1) m = fmaxf(m, __shfl_down(m, off, 32));
    m = __shfl(m, 0, 32);
    float e = expf(am - m);
    __syncthreads();
    // exact rank (ties broken by index, matching top_k semantics)
    int rk = 0;
    #pragma unroll 8
    for (int dd=0; dd<32; dd++){
        float av = Am[c][dd];
        rk += (av > am) || (av == am && dd < d);
    }
    float e0 = rk < 16 ? e : 0.f;
    float e1 = rk < 21 ? e : 0.f;
    float e2 = rk < 24 ? e : 0.f;
    float e3 = rk < 25 ? e : 0.f;
    #pragma unroll
    for (int off=16; off>0; off>>=1){
        e0 += __shfl_down(e0, off, 32);
        e1 += __shfl_down(e1, off, 32);
        e2 += __shfl_down(e2, off, 32);
        e3 += __shfl_down(e3, off, 32);
    }
    float d0 = __shfl(e0, 0, 32), d1 = __shfl(e1, 0, 32);
    float d2 = __shfl(e2, 0, 32), d3 = __shfl(e3, 0, 32);
    float s = (rk<16 ? A1[0]/d0 : 0.f) + (rk<21 ? A2[0]/d1 : 0.f)
            + (rk<24 ? A3[0]/d2 : 0.f) + (rk<25 ? A4[0]/d3 : 0.f);
    comb[(size_t)bh*1024 + t] = e * s;
}

// ---- K4a: out = comb @ v, exact GeLU, store TRANSPOSED g[b][n][192] bf16 ----
// v2: bf16 v reads. grid (64, 4, 2), block 256
__global__ void k_applyv(const unsigned short* __restrict__ dwoutB, const float* __restrict__ comb,
                         unsigned short* __restrict__ gT){
    __shared__ float cm[3072];
    int tid = threadIdx.x;
    int b = blockIdx.y;
    int hz = blockIdx.z * 3;
    int n = blockIdx.x*256 + tid;
    #pragma unroll
    for (int j=0;j<12;j++) cm[tid + j*256] = comb[b*6144 + hz*1024 + tid + j*256];
    __syncthreads();
    const unsigned short* vb = dwoutB + (size_t)(b*576 + 384 + hz*32)*NP + n;
    unsigned short* gp = gT + (size_t)(b*NP + n)*192 + hz*32;
    #pragma unroll 1
    for (int h=0;h<3;h++){
        float v[32];
        #pragma unroll
        for (int d=0;d<32;d++) v[d] = bf2f(vb[(size_t)(h*32+d)*NP]);
        const float* chp = &cm[h*1024];
        #pragma unroll 1
        for (int cg=0;cg<4;cg++){
            float s[8];
            #pragma unroll
            for (int i=0;i<8;i++){
                const float* crow = chp + (cg*8+i)*32;
                float acc = 0.f;
                #pragma unroll
                for (int d=0;d<32;d++) acc += crow[d]*v[d];
                s[i] = 0.5f*acc*(1.f + erff(acc*0.70710678118654752f));
            }
            u32x4 pk;
            pk.x = pk2(s[0],s[1]); pk.y = pk2(s[2],s[3]);
            pk.z = pk2(s[4],s[5]); pk.w = pk2(s[6],s[7]);
            *(u32x4*)(gp + h*32 + cg*8) = pk;
        }
    }
}

// ---- K4b: proj GEMM at low res + nearest 2x upsample ----
// grid (128, 4), block 256
__global__ __launch_bounds__(256, 2)
void k_proj(const unsigned short* __restrict__ gT, const unsigned short* __restrict__ Pbf,
            float* __restrict__ out){
    __shared__ unsigned short Bl[128*200];  // [pos][K=192 + pad8]
    int tid = threadIdx.x;
    int lane = tid & 63, wv = tid >> 6;
    int n16 = lane & 15, quad = lane >> 4;
    int y2 = blockIdx.x, b = blockIdx.y;

    // ---- stage B once: contiguous 98KB, fully coalesced 16B/lane ----
    #pragma unroll 6
    for (int j=0;j<12;j++){
        int idx = tid + j*256;
        int r = idx / 24, g = idx - r*24;
        *(u32x4*)&Bl[r*200 + g*8] =
            *(const u32x4*)(gT + ((size_t)(b*NP + y2*128 + r)*192 + g*8));
    }
    bf16x8 afc[3], afn[3];
    #pragma unroll
    for (int j=0;j<3;j++)
        afc[j] = *(const bf16x8*)(Pbf + (size_t)(((wv*3+j)*16 + n16)*192 + quad*8));
    __syncthreads();

    f32x4 acc[3][8];
    #pragma unroll
    for (int j=0;j<3;j++)
      #pragma unroll
      for (int s=0;s<8;s++)
        acc[j][s] = (f32x4){0.f,0.f,0.f,0.f};

    #pragma unroll 1
    for (int it=0; it<6; it++){
        if (it < 5){
            #pragma unroll
            for (int j=0;j<3;j++)
                afn[j] = *(const bf16x8*)(Pbf +
                    (size_t)(((wv*3+j)*16 + n16)*192 + (it+1)*32 + quad*8));
        }
        int bko = it*32 + quad*8;
        bf16x8 bfr[8];
        #pragma unroll
        for (int s=0;s<8;s++) bfr[s] = *(const bf16x8*)&Bl[(s*16 + n16)*200 + bko];
        #pragma unroll
        for (int j=0;j<3;j++)
          #pragma unroll
          for (int s=0;s<8;s++)
            acc[j][s] = __builtin_amdgcn_mfma_f32_16x16x32_bf16(afc[j], bfr[s], acc[j][s], 0,0,0);
        #pragma unroll
        for (int j=0;j<3;j++) afc[j] = afn[j];
    }

    #pragma unroll
    for (int j=0;j<3;j++){
        int oc = (wv*3+j)*16 + quad*4;
        #pragma unroll
        for (int sp=0;sp<8;sp++){
            int x2 = sp*16 + n16;
            #pragma unroll
            for (int r=0;r<4;r++){
                float v = acc[j][sp][r];
                size_t o = ((size_t)(b*192 + oc + r)*256 + 2*y2)*256 + 2*x2;
                float2 val = make_float2(v, v);
                *(float2*)(out + o) = val;
                *(float2*)(out + o + 256) = val;
            }
        }
    }
}

extern "C" void kernel_launch(void* const* d_in, const int* in_sizes, int n_in,
                              void* d_out, int out_size, void* d_ws, size_t ws_size,
                              hipStream_t stream){
    const float* x     = (const float*)d_in[0];
    const float* temp  = (const float*)d_in[1];
    const float* qkvw  = (const float*)d_in[2];
    const float* dww   = (const float*)d_in[3];
    const float* projw = (const float*)d_in[4];
    const float* A1    = (const float*)d_in[5];
    const float* A2    = (const float*)d_in[6];
    const float* A3    = (const float*)d_in[7];
    const float* A4    = (const float*)d_in[8];
    float* out = (float*)d_out;
    char* ws = (char*)d_ws;

    // workspace layout (bytes)
    unsigned short* dwoutB = (unsigned short*)ws;                    // 75,497,472
    unsigned short* qkvp   = (unsigned short*)(ws + 75497472ull);    // 75,497,472
    unsigned short* gT     = (unsigned short*)(ws + 75497472ull);    // overlaps qkvp (dead by then)
    unsigned short* Wbf    = (unsigned short*)(ws + 150994944ull);   // 221,184
    unsigned short* Pbf    = (unsigned short*)(ws + 151216128ull);   // 73,728
    float*          attn   = (float*)(ws + 151289856ull);            // 98,304
    float*          comb   = (float*)(ws + 151388160ull);            // 98,304
    float*          sumsq  = (float*)(ws + 151486464ull);            // 6,144

    hipMemsetAsync(attn, 0, 98304, stream);
    hipMemsetAsync(sumsq, 0, 6144, stream);
    k_convert<<<dim3((110592+255)/256), dim3(256), 0, stream>>>(qkvw, Wbf, 110592);
    k_convert<<<dim3((36864+255)/256), dim3(256), 0, stream>>>(projw, Pbf, 36864);
    k_qkvpool<<<dim3(512,4), dim3(384), 0, stream>>>(x, Wbf, qkvp);
    k_dwconv<<<dim3(8,576,4), dim3(256), 0, stream>>>(qkvp, dww, dwoutB, sumsq);
    k_attnraw<<<dim3(32,6,4), dim3(256), 0, stream>>>(dwoutB, attn);
    k_mask_softmax<<<dim3(24), dim3(1024), 0, stream>>>(attn, sumsq, temp, A1, A2, A3, A4, comb);
    k_applyv<<<dim3(64,4,2), dim3(256), 0, stream>>>(dwoutB, comb, gT);
    k_proj<<<dim3(128,4), dim3(256), 0, stream>>>(gT, Pbf, out);
}

// Round 5
// 564.021 us; speedup vs baseline: 1.0766x; 1.0766x over previous
//
#include <hip/hip_runtime.h>
#include <hip/hip_bf16.h>
#include <math.h>

typedef __attribute__((ext_vector_type(8))) short bf16x8;
typedef __attribute__((ext_vector_type(4))) float f32x4;
typedef __attribute__((ext_vector_type(4))) unsigned int u32x4;

#define NP 16384
#define HWFULL 65536

__device__ __forceinline__ unsigned short f2bf(float f){
    union { float f; unsigned int u; } v; v.f = f;
    unsigned int u = v.u;
    u += 0x7fffu + ((u >> 16) & 1u);
    return (unsigned short)(u >> 16);
}
__device__ __forceinline__ float bf2f(unsigned short h){
    union { unsigned int u; float f; } v; v.u = ((unsigned int)h) << 16;
    return v.f;
}
// HW packed bf16 convert (RNE, identical rounding to f2bf): 1 instr vs ~10
__device__ __forceinline__ unsigned int pk2(float a, float b){
    unsigned int r;
    asm("v_cvt_pk_bf16_f32 %0, %1, %2" : "=v"(r) : "v"(a), "v"(b));
    return r;
}

// ---- K0: fp32 -> bf16 weight conversion ----
__global__ void k_convert(const float* __restrict__ s, unsigned short* __restrict__ d, int n){
    int i = blockIdx.x * 256 + threadIdx.x;
    if (i < n) d[i] = f2bf(s[i]);
}

// ---- K1: qkv 1x1 conv (bf16 MFMA GEMM) fused with 2x2 maxpool ----
// v4 structure (measured fixed point ~170us across 5 variants — do not retune
// params; occupancy (R1,R4) and staging pattern (R2) variants all neutral/worse).
// grid (512, 4): bx -> (y2 = bx>>2, x2blk = bx&3); by = b
__global__ __launch_bounds__(256, 2)
void k_qkvpool(const float* __restrict__ x, const unsigned short* __restrict__ Wbf,
               unsigned short* __restrict__ qkvp){
    __shared__ unsigned short Bl[128*200];  // [pos][K=192 + pad8] bf16, persistent
    __shared__ unsigned short Ep[192*36];   // pooled epilogue buffer
    int tid = threadIdx.x;
    int lane = tid & 63, wv = tid >> 6;
    int n16 = lane & 15, quad = lane >> 4;
    int bx = blockIdx.x;
    int y2 = bx >> 2, x2blk = bx & 3;
    int b = blockIdx.y;

    // ---- stage B: transpose-gather x[ic][pos] -> Bl[pos][ic], fp32->bf16, full K ----
    #pragma unroll 6
    for (int j=0;j<12;j++){
        int idx = tid + j*256;
        int g = idx >> 7, w = idx & 127;       // g: ic granule of 8; w: 0..63 row y, 64..127 row y+1
        int y = y2*2 + (w >> 6);
        int xc = x2blk*64 + (w & 63);
        const float* xp = x + (size_t)(b*192 + g*8) * HWFULL + y*256 + xc;
        float v0 = xp[0];
        float v1 = xp[(size_t)1*HWFULL];
        float v2 = xp[(size_t)2*HWFULL];
        float v3 = xp[(size_t)3*HWFULL];
        float v4 = xp[(size_t)4*HWFULL];
        float v5 = xp[(size_t)5*HWFULL];
        float v6 = xp[(size_t)6*HWFULL];
        float v7 = xp[(size_t)7*HWFULL];
        u32x4 pk;
        pk.x = pk2(v0,v1); pk.y = pk2(v2,v3); pk.z = pk2(v4,v5); pk.w = pk2(v6,v7);
        *(u32x4*)&Bl[w*200 + g*8] = pk;
    }
    // preload A fragments for (ocblk=0, it=0) — independent of LDS
    bf16x8 afc[3], afn[3];
    #pragma unroll
    for (int j=0;j<3;j++)
        afc[j] = *(const bf16x8*)(Wbf + (size_t)(((wv*3+j)*16 + n16)*192 + quad*8));
    __syncthreads();

    for (int ocblk=0; ocblk<3; ocblk++){
        f32x4 acc[3][8];
        #pragma unroll
        for (int j=0;j<3;j++)
          #pragma unroll
          for (int s=0;s<8;s++)
            acc[j][s] = (f32x4){0.f,0.f,0.f,0.f};

        #pragma unroll 1
        for (int it=0; it<6; it++){
            int nocb = (it==5) ? ocblk+1 : ocblk;
            int nit  = (it==5) ? 0 : it+1;
            if (nocb < 3){
                #pragma unroll
                for (int j=0;j<3;j++)
                    afn[j] = *(const bf16x8*)(Wbf +
                        (size_t)((nocb*192 + (wv*3+j)*16 + n16)*192 + nit*32 + quad*8));
            }
            int bko = it*32 + quad*8;
            bf16x8 bfr[8];
            #pragma unroll
            for (int s=0;s<8;s++) bfr[s] = *(const bf16x8*)&Bl[(s*16 + n16)*200 + bko];
            #pragma unroll
            for (int j=0;j<3;j++)
              #pragma unroll
              for (int s=0;s<8;s++)
                acc[j][s] = __builtin_amdgcn_mfma_f32_16x16x32_bf16(afc[j], bfr[s], acc[j][s], 0,0,0);
            #pragma unroll
            for (int j=0;j<3;j++) afc[j] = afn[j];
        }
        __syncthreads();   // prev ocblk's cooperative-store reads of Ep done
        // ---- epilogue: 2x2 maxpool into LDS (strip sp & sp+4 = rows y,y+1; lane^1 = x,x+1)
        #pragma unroll
        for (int j=0;j<3;j++){
            int ocr = (wv*3+j)*16 + quad*4;
            #pragma unroll
            for (int sp=0;sp<4;sp++){
                #pragma unroll
                for (int r=0;r<4;r++){
                    float v = fmaxf(acc[j][sp][r], acc[j][sp+4][r]);
                    float o = __shfl_xor(v, 1, 64);
                    v = fmaxf(v, o);
                    if ((n16 & 1) == 0)
                        Ep[(ocr + r)*36 + sp*8 + (n16 >> 1)] = f2bf(v);
                }
            }
        }
        __syncthreads();
        // ---- cooperative coalesced store: 192 rows x 32 shorts (64B/row) ----
        size_t rowbase = (size_t)(b*576 + ocblk*192)*NP + y2*128 + x2blk*32;
        #pragma unroll
        for (int it2=0; it2<6; it2++){
            int c = tid + it2*256;
            int row = c >> 3, seg = c & 7;
            uint2 vv = *(const uint2*)&Ep[row*36 + seg*4];
            *(uint2*)(qkvp + rowbase + (size_t)row*NP + seg*4) = vv;
        }
    }
}

// ---- K2: depthwise 3x3 SAME conv + per-channel sum-of-squares (q,k only) ----
// v3: bf16 OUTPUT (halves dwout traffic); ssq still from fp32 values.
// grid (8, 576, 4), block 256
__global__ void k_dwconv(const unsigned short* __restrict__ qkvp, const float* __restrict__ dww,
                         unsigned short* __restrict__ dwoutB, float* __restrict__ sumsq){
    __shared__ float sl[18*132];   // [row][gx+2], gx in [-1,128] -> idx 1..130
    int tid = threadIdx.x;
    int y0 = blockIdx.x * 16;
    int ch = blockIdx.y;
    int b  = blockIdx.z;
    const unsigned short* in = qkvp + (size_t)(b*576 + ch) * NP;
    int l = tid & 63, wr = tid >> 6;
    #pragma unroll
    for (int j=0;j<5;j++){
        int row = wr + j*4;
        if (row < 18){
            int gy = y0 - 1 + row;
            float2 v = make_float2(0.f, 0.f);
            if (gy >= 0 && gy < 128){
                unsigned int u = *(const unsigned int*)&in[gy*128 + l*2];
                v.x = bf2f((unsigned short)(u & 0xffffu));
                v.y = bf2f((unsigned short)(u >> 16));
            }
            *(float2*)&sl[row*132 + 2 + l*2] = v;
        }
    }
    if (tid < 18) sl[tid*132 + 1] = 0.f;              // left halo (gx=-1)
    else if (tid < 36) sl[(tid-18)*132 + 130] = 0.f;  // right halo (gx=128)
    float w0 = dww[ch*9+0], w1 = dww[ch*9+1], w2 = dww[ch*9+2];
    float w3 = dww[ch*9+3], w4 = dww[ch*9+4], w5 = dww[ch*9+5];
    float w6 = dww[ch*9+6], w7 = dww[ch*9+7], w8 = dww[ch*9+8];
    __syncthreads();
    unsigned short* outp = dwoutB + (size_t)(b*576 + ch) * NP;
    int col = tid & 127, half = tid >> 7;
    float ssq = 0.f;
    int base = (half*8)*132 + col + 1;   // sl[row][col-1] of first input row
    float r0a=sl[base],     r0b=sl[base+1],   r0c=sl[base+2];
    float r1a=sl[base+132], r1b=sl[base+133], r1c=sl[base+134];
    #pragma unroll
    for (int i=0;i<8;i++){
        const float* r2 = &sl[base + (i+2)*132];
        float r2a=r2[0], r2b=r2[1], r2c=r2[2];
        float a = r0a*w0 + r0b*w1 + r0c*w2
                + r1a*w3 + r1b*w4 + r1c*w5
                + r2a*w6 + r2b*w7 + r2c*w8;
        outp[(y0 + half*8 + i)*128 + col] = f2bf(a);
        ssq += a*a;
        r0a=r1a; r0b=r1b; r0c=r1c;
        r1a=r2a; r1b=r2b; r1c=r2c;
    }
    if (ch < 384){
        #pragma unroll
        for (int off=32; off>0; off>>=1) ssq += __shfl_down(ssq, off, 64);
        if ((tid & 63) == 0) atomicAdd(&sumsq[b*384 + ch], ssq);
    }
}

// ---- K3a: raw attention gram matrix v3 — MFMA direct from global bf16 ----
// attn[c][d] = sum_n q[c][n]*k[d][n]: both operand fragments are [row][contig n]
// = exactly dwoutB's layout -> bf16x8 global loads, NO LDS staging, no transpose.
// Per wave: 128 n = 4 K-steps x 4 MFMA. Cross-wave LDS reduce + one atomicAdd.
// grid (32, 6, 4), block 256
__global__ __launch_bounds__(256) void k_attnraw(const unsigned short* __restrict__ dwoutB,
                                                 float* __restrict__ attn){
    __shared__ float red[4][32][33];   // 16.9 KB
    int tid = threadIdx.x;
    int lane = tid & 63, wv = tid >> 6;
    int n16 = lane & 15, quad = lane >> 4;
    int h = blockIdx.y, b = blockIdx.z;
    int n0 = blockIdx.x * 512 + wv * 128;
    const unsigned short* qb = dwoutB + (size_t)(b*576 + h*32)*NP;
    const unsigned short* kb = dwoutB + (size_t)(b*576 + 192 + h*32)*NP;

    f32x4 acc[2][2];
    #pragma unroll
    for (int i=0;i<2;i++)
      #pragma unroll
      for (int j=0;j<2;j++) acc[i][j] = (f32x4){0.f,0.f,0.f,0.f};

    #pragma unroll
    for (int ks=0; ks<4; ks++){
        int n = n0 + ks*32 + quad*8;
        bf16x8 aq0 = *(const bf16x8*)(qb + (size_t)(n16)*NP + n);
        bf16x8 aq1 = *(const bf16x8*)(qb + (size_t)(16 + n16)*NP + n);
        bf16x8 bk0 = *(const bf16x8*)(kb + (size_t)(n16)*NP + n);
        bf16x8 bk1 = *(const bf16x8*)(kb + (size_t)(16 + n16)*NP + n);
        acc[0][0] = __builtin_amdgcn_mfma_f32_16x16x32_bf16(aq0, bk0, acc[0][0], 0,0,0);
        acc[0][1] = __builtin_amdgcn_mfma_f32_16x16x32_bf16(aq0, bk1, acc[0][1], 0,0,0);
        acc[1][0] = __builtin_amdgcn_mfma_f32_16x16x32_bf16(aq1, bk0, acc[1][0], 0,0,0);
        acc[1][1] = __builtin_amdgcn_mfma_f32_16x16x32_bf16(aq1, bk1, acc[1][1], 0,0,0);
    }
    // C layout (proven in k_proj epilogue): row = cc*16 + quad*4 + r, col = dd*16 + n16
    #pragma unroll
    for (int cc=0; cc<2; cc++)
      #pragma unroll
      for (int dd=0; dd<2; dd++)
        #pragma unroll
        for (int r=0; r<4; r++)
          red[wv][cc*16 + quad*4 + r][dd*16 + n16] = acc[cc][dd][r];
    __syncthreads();
    float* ap = attn + (size_t)(b*6+h)*1024;
    #pragma unroll
    for (int j=0;j<4;j++){
        int o = tid + j*256;
        int c = o >> 5, d = o & 31;
        float v = red[0][c][d] + red[1][c][d] + red[2][c][d] + red[3][c][d];
        atomicAdd(ap + o, v);
    }
}

// ---- K3b: normalize, temperature, 4x top-k masked softmax, combine ----
// v2: fully wave-parallel — 1024 threads, one per (c,d); shfl-reduce rows.
// grid 24, block 1024
__global__ void k_mask_softmax(const float* __restrict__ attn, const float* __restrict__ sumsq,
                               const float* __restrict__ temp,
                               const float* __restrict__ A1, const float* __restrict__ A2,
                               const float* __restrict__ A3, const float* __restrict__ A4,
                               float* __restrict__ comb){
    __shared__ float Am[32][33];
    __shared__ float qn[32], kn[32];
    int t = threadIdx.x;
    int bh = blockIdx.x;
    int b = bh / 6, h = bh % 6;
    if (t < 32) qn[t] = fmaxf(sqrtf(sumsq[b*384 + h*32 + t]), 1e-12f);
    else if (t >= 64 && t < 96) kn[t-64] = fmaxf(sqrtf(sumsq[b*384 + 192 + h*32 + (t-64)]), 1e-12f);
    __syncthreads();
    int c = t >> 5, d = t & 31;
    float tv = temp[h];
    float am = attn[(size_t)bh*1024 + t] * tv / (qn[c]*kn[d]);
    Am[c][d] = am;
    // row max (32-lane subgroups)
    float m = am;
    #pragma unroll
    for (int off=16; off>0; off>>=1) m = fmaxf(m, __shfl_down(m, off, 32));
    m = __shfl(m, 0, 32);
    float e = expf(am - m);
    __syncthreads();
    // exact rank (ties broken by index, matching top_k semantics)
    int rk = 0;
    #pragma unroll 8
    for (int dd=0; dd<32; dd++){
        float av = Am[c][dd];
        rk += (av > am) || (av == am && dd < d);
    }
    float e0 = rk < 16 ? e : 0.f;
    float e1 = rk < 21 ? e : 0.f;
    float e2 = rk < 24 ? e : 0.f;
    float e3 = rk < 25 ? e : 0.f;
    #pragma unroll
    for (int off=16; off>0; off>>=1){
        e0 += __shfl_down(e0, off, 32);
        e1 += __shfl_down(e1, off, 32);
        e2 += __shfl_down(e2, off, 32);
        e3 += __shfl_down(e3, off, 32);
    }
    float d0 = __shfl(e0, 0, 32), d1 = __shfl(e1, 0, 32);
    float d2 = __shfl(e2, 0, 32), d3 = __shfl(e3, 0, 32);
    float s = (rk<16 ? A1[0]/d0 : 0.f) + (rk<21 ? A2[0]/d1 : 0.f)
            + (rk<24 ? A3[0]/d2 : 0.f) + (rk<25 ? A4[0]/d3 : 0.f);
    comb[(size_t)bh*1024 + t] = e * s;
}

// ---- K4a: out = comb @ v, exact GeLU, store TRANSPOSED g[b][n][192] bf16 ----
// v2: bf16 v reads. grid (64, 4, 2), block 256
__global__ void k_applyv(const unsigned short* __restrict__ dwoutB, const float* __restrict__ comb,
                         unsigned short* __restrict__ gT){
    __shared__ float cm[3072];
    int tid = threadIdx.x;
    int b = blockIdx.y;
    int hz = blockIdx.z * 3;
    int n = blockIdx.x*256 + tid;
    #pragma unroll
    for (int j=0;j<12;j++) cm[tid + j*256] = comb[b*6144 + hz*1024 + tid + j*256];
    __syncthreads();
    const unsigned short* vb = dwoutB + (size_t)(b*576 + 384 + hz*32)*NP + n;
    unsigned short* gp = gT + (size_t)(b*NP + n)*192 + hz*32;
    #pragma unroll 1
    for (int h=0;h<3;h++){
        float v[32];
        #pragma unroll
        for (int d=0;d<32;d++) v[d] = bf2f(vb[(size_t)(h*32+d)*NP]);
        const float* chp = &cm[h*1024];
        #pragma unroll 1
        for (int cg=0;cg<4;cg++){
            float s[8];
            #pragma unroll
            for (int i=0;i<8;i++){
                const float* crow = chp + (cg*8+i)*32;
                float acc = 0.f;
                #pragma unroll
                for (int d=0;d<32;d++) acc += crow[d]*v[d];
                s[i] = 0.5f*acc*(1.f + erff(acc*0.70710678118654752f));
            }
            u32x4 pk;
            pk.x = pk2(s[0],s[1]); pk.y = pk2(s[2],s[3]);
            pk.z = pk2(s[4],s[5]); pk.w = pk2(s[6],s[7]);
            *(u32x4*)(gp + h*32 + cg*8) = pk;
        }
    }
}

// ---- K4b: proj GEMM at low res + nearest 2x upsample ----
// grid (128, 4), block 256
__global__ __launch_bounds__(256, 2)
void k_proj(const unsigned short* __restrict__ gT, const unsigned short* __restrict__ Pbf,
            float* __restrict__ out){
    __shared__ unsigned short Bl[128*200];  // [pos][K=192 + pad8]
    int tid = threadIdx.x;
    int lane = tid & 63, wv = tid >> 6;
    int n16 = lane & 15, quad = lane >> 4;
    int y2 = blockIdx.x, b = blockIdx.y;

    // ---- stage B once: contiguous 98KB, fully coalesced 16B/lane ----
    #pragma unroll 6
    for (int j=0;j<12;j++){
        int idx = tid + j*256;
        int r = idx / 24, g = idx - r*24;
        *(u32x4*)&Bl[r*200 + g*8] =
            *(const u32x4*)(gT + ((size_t)(b*NP + y2*128 + r)*192 + g*8));
    }
    bf16x8 afc[3], afn[3];
    #pragma unroll
    for (int j=0;j<3;j++)
        afc[j] = *(const bf16x8*)(Pbf + (size_t)(((wv*3+j)*16 + n16)*192 + quad*8));
    __syncthreads();

    f32x4 acc[3][8];
    #pragma unroll
    for (int j=0;j<3;j++)
      #pragma unroll
      for (int s=0;s<8;s++)
        acc[j][s] = (f32x4){0.f,0.f,0.f,0.f};

    #pragma unroll 1
    for (int it=0; it<6; it++){
        if (it < 5){
            #pragma unroll
            for (int j=0;j<3;j++)
                afn[j] = *(const bf16x8*)(Pbf +
                    (size_t)(((wv*3+j)*16 + n16)*192 + (it+1)*32 + quad*8));
        }
        int bko = it*32 + quad*8;
        bf16x8 bfr[8];
        #pragma unroll
        for (int s=0;s<8;s++) bfr[s] = *(const bf16x8*)&Bl[(s*16 + n16)*200 + bko];
        #pragma unroll
        for (int j=0;j<3;j++)
          #pragma unroll
          for (int s=0;s<8;s++)
            acc[j][s] = __builtin_amdgcn_mfma_f32_16x16x32_bf16(afc[j], bfr[s], acc[j][s], 0,0,0);
        #pragma unroll
        for (int j=0;j<3;j++) afc[j] = afn[j];
    }

    #pragma unroll
    for (int j=0;j<3;j++){
        int oc = (wv*3+j)*16 + quad*4;
        #pragma unroll
        for (int sp=0;sp<8;sp++){
            int x2 = sp*16 + n16;
            #pragma unroll
            for (int r=0;r<4;r++){
                float v = acc[j][sp][r];
                size_t o = ((size_t)(b*192 + oc + r)*256 + 2*y2)*256 + 2*x2;
                float2 val = make_float2(v, v);
                *(float2*)(out + o) = val;
                *(float2*)(out + o + 256) = val;
            }
        }
    }
}

extern "C" void kernel_launch(void* const* d_in, const int* in_sizes, int n_in,
                              void* d_out, int out_size, void* d_ws, size_t ws_size,
                              hipStream_t stream){
    const float* x     = (const float*)d_in[0];
    const float* temp  = (const float*)d_in[1];
    const float* qkvw  = (const float*)d_in[2];
    const float* dww   = (const float*)d_in[3];
    const float* projw = (const float*)d_in[4];
    const float* A1    = (const float*)d_in[5];
    const float* A2    = (const float*)d_in[6];
    const float* A3    = (const float*)d_in[7];
    const float* A4    = (const float*)d_in[8];
    float* out = (float*)d_out;
    char* ws = (char*)d_ws;

    // workspace layout (bytes)
    unsigned short* dwoutB = (unsigned short*)ws;                    // 75,497,472
    unsigned short* qkvp   = (unsigned short*)(ws + 75497472ull);    // 75,497,472
    unsigned short* gT     = (unsigned short*)(ws + 75497472ull);    // overlaps qkvp (dead by then)
    unsigned short* Wbf    = (unsigned short*)(ws + 150994944ull);   // 221,184
    unsigned short* Pbf    = (unsigned short*)(ws + 151216128ull);   // 73,728
    float*          attn   = (float*)(ws + 151289856ull);            // 98,304
    float*          comb   = (float*)(ws + 151388160ull);            // 98,304
    float*          sumsq  = (float*)(ws + 151486464ull);            // 6,144

    hipMemsetAsync(attn, 0, 98304, stream);
    hipMemsetAsync(sumsq, 0, 6144, stream);
    k_convert<<<dim3((110592+255)/256), dim3(256), 0, stream>>>(qkvw, Wbf, 110592);
    k_convert<<<dim3((36864+255)/256), dim3(256), 0, stream>>>(projw, Pbf, 36864);
    k_qkvpool<<<dim3(512,4), dim3(256), 0, stream>>>(x, Wbf, qkvp);
    k_dwconv<<<dim3(8,576,4), dim3(256), 0, stream>>>(qkvp, dww, dwoutB, sumsq);
    k_attnraw<<<dim3(32,6,4), dim3(256), 0, stream>>>(dwoutB, attn);
    k_mask_softmax<<<dim3(24), dim3(1024), 0, stream>>>(attn, sumsq, temp, A1, A2, A3, A4, comb);
    k_applyv<<<dim3(64,4,2), dim3(256), 0, stream>>>(dwoutB, comb, gT);
    k_proj<<<dim3(128,4), dim3(256), 0, stream>>>(gT, Pbf, out);
}

// Round 6
// 546.377 us; speedup vs baseline: 1.1114x; 1.0323x over previous
//
#include <hip/hip_runtime.h>
#include <hip/hip_bf16.h>
#include <math.h>

typedef __attribute__((ext_vector_type(8))) short bf16x8;
typedef __attribute__((ext_vector_type(4))) float f32x4;
typedef __attribute__((ext_vector_type(4))) unsigned int u32x4;

#define NP 16384
#define HWFULL 65536

__device__ __forceinline__ unsigned short f2bf(float f){
    union { float f; unsigned int u; } v; v.f = f;
    unsigned int u = v.u;
    u += 0x7fffu + ((u >> 16) & 1u);
    return (unsigned short)(u >> 16);
}
__device__ __forceinline__ float bf2f(unsigned short h){
    union { unsigned int u; float f; } v; v.u = ((unsigned int)h) << 16;
    return v.f;
}
// HW packed bf16 convert (RNE, identical rounding to f2bf): 1 instr vs ~10
__device__ __forceinline__ unsigned int pk2(float a, float b){
    unsigned int r;
    asm("v_cvt_pk_bf16_f32 %0, %1, %2" : "=v"(r) : "v"(a), "v"(b));
    return r;
}

// ---- K0: fp32 -> bf16 weight conversion (qkv + proj in one launch) ----
__global__ void k_convert2(const float* __restrict__ qw, const float* __restrict__ pw,
                           unsigned short* __restrict__ Wbf, unsigned short* __restrict__ Pbf){
    int i = blockIdx.x * 256 + threadIdx.x;
    if (i < 110592) Wbf[i] = f2bf(qw[i]);
    else if (i < 110592 + 36864) Pbf[i - 110592] = f2bf(pw[i - 110592]);
}

// ---- K1: qkv 1x1 conv (bf16 MFMA GEMM) fused with 2x2 maxpool ----
// v4 structure (measured fixed point ~170us across 5 variants — do not retune).
// grid (512, 4): bx -> (y2 = bx>>2, x2blk = bx&3); by = b
__global__ __launch_bounds__(256, 2)
void k_qkvpool(const float* __restrict__ x, const unsigned short* __restrict__ Wbf,
               unsigned short* __restrict__ qkvp){
    __shared__ unsigned short Bl[128*200];  // [pos][K=192 + pad8] bf16, persistent
    __shared__ unsigned short Ep[192*36];   // pooled epilogue buffer
    int tid = threadIdx.x;
    int lane = tid & 63, wv = tid >> 6;
    int n16 = lane & 15, quad = lane >> 4;
    int bx = blockIdx.x;
    int y2 = bx >> 2, x2blk = bx & 3;
    int b = blockIdx.y;

    // ---- stage B: transpose-gather x[ic][pos] -> Bl[pos][ic], fp32->bf16, full K ----
    #pragma unroll 6
    for (int j=0;j<12;j++){
        int idx = tid + j*256;
        int g = idx >> 7, w = idx & 127;       // g: ic granule of 8; w: 0..63 row y, 64..127 row y+1
        int y = y2*2 + (w >> 6);
        int xc = x2blk*64 + (w & 63);
        const float* xp = x + (size_t)(b*192 + g*8) * HWFULL + y*256 + xc;
        float v0 = xp[0];
        float v1 = xp[(size_t)1*HWFULL];
        float v2 = xp[(size_t)2*HWFULL];
        float v3 = xp[(size_t)3*HWFULL];
        float v4 = xp[(size_t)4*HWFULL];
        float v5 = xp[(size_t)5*HWFULL];
        float v6 = xp[(size_t)6*HWFULL];
        float v7 = xp[(size_t)7*HWFULL];
        u32x4 pk;
        pk.x = pk2(v0,v1); pk.y = pk2(v2,v3); pk.z = pk2(v4,v5); pk.w = pk2(v6,v7);
        *(u32x4*)&Bl[w*200 + g*8] = pk;
    }
    // preload A fragments for (ocblk=0, it=0) — independent of LDS
    bf16x8 afc[3], afn[3];
    #pragma unroll
    for (int j=0;j<3;j++)
        afc[j] = *(const bf16x8*)(Wbf + (size_t)(((wv*3+j)*16 + n16)*192 + quad*8));
    __syncthreads();

    for (int ocblk=0; ocblk<3; ocblk++){
        f32x4 acc[3][8];
        #pragma unroll
        for (int j=0;j<3;j++)
          #pragma unroll
          for (int s=0;s<8;s++)
            acc[j][s] = (f32x4){0.f,0.f,0.f,0.f};

        #pragma unroll 1
        for (int it=0; it<6; it++){
            int nocb = (it==5) ? ocblk+1 : ocblk;
            int nit  = (it==5) ? 0 : it+1;
            if (nocb < 3){
                #pragma unroll
                for (int j=0;j<3;j++)
                    afn[j] = *(const bf16x8*)(Wbf +
                        (size_t)((nocb*192 + (wv*3+j)*16 + n16)*192 + nit*32 + quad*8));
            }
            int bko = it*32 + quad*8;
            bf16x8 bfr[8];
            #pragma unroll
            for (int s=0;s<8;s++) bfr[s] = *(const bf16x8*)&Bl[(s*16 + n16)*200 + bko];
            #pragma unroll
            for (int j=0;j<3;j++)
              #pragma unroll
              for (int s=0;s<8;s++)
                acc[j][s] = __builtin_amdgcn_mfma_f32_16x16x32_bf16(afc[j], bfr[s], acc[j][s], 0,0,0);
            #pragma unroll
            for (int j=0;j<3;j++) afc[j] = afn[j];
        }
        __syncthreads();   // prev ocblk's cooperative-store reads of Ep done
        // ---- epilogue: 2x2 maxpool into LDS (strip sp & sp+4 = rows y,y+1; lane^1 = x,x+1)
        #pragma unroll
        for (int j=0;j<3;j++){
            int ocr = (wv*3+j)*16 + quad*4;
            #pragma unroll
            for (int sp=0;sp<4;sp++){
                #pragma unroll
                for (int r=0;r<4;r++){
                    float v = fmaxf(acc[j][sp][r], acc[j][sp+4][r]);
                    float o = __shfl_xor(v, 1, 64);
                    v = fmaxf(v, o);
                    if ((n16 & 1) == 0)
                        Ep[(ocr + r)*36 + sp*8 + (n16 >> 1)] = f2bf(v);
                }
            }
        }
        __syncthreads();
        // ---- cooperative coalesced store: 192 rows x 32 shorts (64B/row) ----
        size_t rowbase = (size_t)(b*576 + ocblk*192)*NP + y2*128 + x2blk*32;
        #pragma unroll
        for (int it2=0; it2<6; it2++){
            int c = tid + it2*256;
            int row = c >> 3, seg = c & 7;
            uint2 vv = *(const uint2*)&Ep[row*36 + seg*4];
            *(uint2*)(qkvp + rowbase + (size_t)row*NP + seg*4) = vv;
        }
    }
}

// ---- K2: depthwise 3x3 SAME conv + per-channel sum-of-squares (q,k only) ----
// v3: bf16 OUTPUT (halves dwout traffic); ssq still from fp32 values.
// grid (8, 576, 4), block 256
__global__ void k_dwconv(const unsigned short* __restrict__ qkvp, const float* __restrict__ dww,
                         unsigned short* __restrict__ dwoutB, float* __restrict__ sumsq){
    __shared__ float sl[18*132];   // [row][gx+2], gx in [-1,128] -> idx 1..130
    int tid = threadIdx.x;
    int y0 = blockIdx.x * 16;
    int ch = blockIdx.y;
    int b  = blockIdx.z;
    const unsigned short* in = qkvp + (size_t)(b*576 + ch) * NP;
    int l = tid & 63, wr = tid >> 6;
    #pragma unroll
    for (int j=0;j<5;j++){
        int row = wr + j*4;
        if (row < 18){
            int gy = y0 - 1 + row;
            float2 v = make_float2(0.f, 0.f);
            if (gy >= 0 && gy < 128){
                unsigned int u = *(const unsigned int*)&in[gy*128 + l*2];
                v.x = bf2f((unsigned short)(u & 0xffffu));
                v.y = bf2f((unsigned short)(u >> 16));
            }
            *(float2*)&sl[row*132 + 2 + l*2] = v;
        }
    }
    if (tid < 18) sl[tid*132 + 1] = 0.f;              // left halo (gx=-1)
    else if (tid < 36) sl[(tid-18)*132 + 130] = 0.f;  // right halo (gx=128)
    float w0 = dww[ch*9+0], w1 = dww[ch*9+1], w2 = dww[ch*9+2];
    float w3 = dww[ch*9+3], w4 = dww[ch*9+4], w5 = dww[ch*9+5];
    float w6 = dww[ch*9+6], w7 = dww[ch*9+7], w8 = dww[ch*9+8];
    __syncthreads();
    unsigned short* outp = dwoutB + (size_t)(b*576 + ch) * NP;
    int col = tid & 127, half = tid >> 7;
    float ssq = 0.f;
    int base = (half*8)*132 + col + 1;   // sl[row][col-1] of first input row
    float r0a=sl[base],     r0b=sl[base+1],   r0c=sl[base+2];
    float r1a=sl[base+132], r1b=sl[base+133], r1c=sl[base+134];
    #pragma unroll
    for (int i=0;i<8;i++){
        const float* r2 = &sl[base + (i+2)*132];
        float r2a=r2[0], r2b=r2[1], r2c=r2[2];
        float a = r0a*w0 + r0b*w1 + r0c*w2
                + r1a*w3 + r1b*w4 + r1c*w5
                + r2a*w6 + r2b*w7 + r2c*w8;
        outp[(y0 + half*8 + i)*128 + col] = f2bf(a);
        ssq += a*a;
        r0a=r1a; r0b=r1b; r0c=r1c;
        r1a=r2a; r1b=r2b; r1c=r2c;
    }
    if (ch < 384){
        #pragma unroll
        for (int off=32; off>0; off>>=1) ssq += __shfl_down(ssq, off, 64);
        if ((tid & 63) == 0) atomicAdd(&sumsq[b*384 + ch], ssq);
    }
}

// ---- K3a: raw attention gram matrix v3 — MFMA direct from global bf16 ----
// grid (32, 6, 4), block 256
__global__ __launch_bounds__(256) void k_attnraw(const unsigned short* __restrict__ dwoutB,
                                                 float* __restrict__ attn){
    __shared__ float red[4][32][33];   // 16.9 KB
    int tid = threadIdx.x;
    int lane = tid & 63, wv = tid >> 6;
    int n16 = lane & 15, quad = lane >> 4;
    int h = blockIdx.y, b = blockIdx.z;
    int n0 = blockIdx.x * 512 + wv * 128;
    const unsigned short* qb = dwoutB + (size_t)(b*576 + h*32)*NP;
    const unsigned short* kb = dwoutB + (size_t)(b*576 + 192 + h*32)*NP;

    f32x4 acc[2][2];
    #pragma unroll
    for (int i=0;i<2;i++)
      #pragma unroll
      for (int j=0;j<2;j++) acc[i][j] = (f32x4){0.f,0.f,0.f,0.f};

    #pragma unroll
    for (int ks=0; ks<4; ks++){
        int n = n0 + ks*32 + quad*8;
        bf16x8 aq0 = *(const bf16x8*)(qb + (size_t)(n16)*NP + n);
        bf16x8 aq1 = *(const bf16x8*)(qb + (size_t)(16 + n16)*NP + n);
        bf16x8 bk0 = *(const bf16x8*)(kb + (size_t)(n16)*NP + n);
        bf16x8 bk1 = *(const bf16x8*)(kb + (size_t)(16 + n16)*NP + n);
        acc[0][0] = __builtin_amdgcn_mfma_f32_16x16x32_bf16(aq0, bk0, acc[0][0], 0,0,0);
        acc[0][1] = __builtin_amdgcn_mfma_f32_16x16x32_bf16(aq0, bk1, acc[0][1], 0,0,0);
        acc[1][0] = __builtin_amdgcn_mfma_f32_16x16x32_bf16(aq1, bk0, acc[1][0], 0,0,0);
        acc[1][1] = __builtin_amdgcn_mfma_f32_16x16x32_bf16(aq1, bk1, acc[1][1], 0,0,0);
    }
    // C layout: row = cc*16 + quad*4 + r, col = dd*16 + n16
    #pragma unroll
    for (int cc=0; cc<2; cc++)
      #pragma unroll
      for (int dd=0; dd<2; dd++)
        #pragma unroll
        for (int r=0; r<4; r++)
          red[wv][cc*16 + quad*4 + r][dd*16 + n16] = acc[cc][dd][r];
    __syncthreads();
    float* ap = attn + (size_t)(b*6+h)*1024;
    #pragma unroll
    for (int j=0;j<4;j++){
        int o = tid + j*256;
        int c = o >> 5, d = o & 31;
        float v = red[0][c][d] + red[1][c][d] + red[2][c][d] + red[3][c][d];
        atomicAdd(ap + o, v);
    }
}

// ---- K3b: normalize, temperature, 4x top-k masked softmax, combine ----
// grid 24, block 1024
__global__ void k_mask_softmax(const float* __restrict__ attn, const float* __restrict__ sumsq,
                               const float* __restrict__ temp,
                               const float* __restrict__ A1, const float* __restrict__ A2,
                               const float* __restrict__ A3, const float* __restrict__ A4,
                               float* __restrict__ comb){
    __shared__ float Am[32][33];
    __shared__ float qn[32], kn[32];
    int t = threadIdx.x;
    int bh = blockIdx.x;
    int b = bh / 6, h = bh % 6;
    if (t < 32) qn[t] = fmaxf(sqrtf(sumsq[b*384 + h*32 + t]), 1e-12f);
    else if (t >= 64 && t < 96) kn[t-64] = fmaxf(sqrtf(sumsq[b*384 + 192 + h*32 + (t-64)]), 1e-12f);
    __syncthreads();
    int c = t >> 5, d = t & 31;
    float tv = temp[h];
    float am = attn[(size_t)bh*1024 + t] * tv / (qn[c]*kn[d]);
    Am[c][d] = am;
    // row max (32-lane subgroups)
    float m = am;
    #pragma unroll
    for (int off=16; off>0; off>>=1) m = fmaxf(m, __shfl_down(m, off, 32));
    m = __shfl(m, 0, 32);
    float e = expf(am - m);
    __syncthreads();
    // exact rank (ties broken by index, matching top_k semantics)
    int rk = 0;
    #pragma unroll 8
    for (int dd=0; dd<32; dd++){
        float av = Am[c][dd];
        rk += (av > am) || (av == am && dd < d);
    }
    float e0 = rk < 16 ? e : 0.f;
    float e1 = rk < 21 ? e : 0.f;
    float e2 = rk < 24 ? e : 0.f;
    float e3 = rk < 25 ? e : 0.f;
    #pragma unroll
    for (int off=16; off>0; off>>=1){
        e0 += __shfl_down(e0, off, 32);
        e1 += __shfl_down(e1, off, 32);
        e2 += __shfl_down(e2, off, 32);
        e3 += __shfl_down(e3, off, 32);
    }
    float d0 = __shfl(e0, 0, 32), d1 = __shfl(e1, 0, 32);
    float d2 = __shfl(e2, 0, 32), d3 = __shfl(e3, 0, 32);
    float s = (rk<16 ? A1[0]/d0 : 0.f) + (rk<21 ? A2[0]/d1 : 0.f)
            + (rk<24 ? A3[0]/d2 : 0.f) + (rk<25 ? A4[0]/d3 : 0.f);
    comb[(size_t)bh*1024 + t] = e * s;
}

// ---- K4: FUSED applyv + proj: g = gelu(comb @ v) built in LDS (bf16, identical
// rounding to the old gT round-trip), then proj GEMM + nearest-2x upsample.
// Saves 50 MB gT traffic + one launch + proj's global staging.
// grid (128, 4), block 256. LDS 75.8 KB -> 2 blocks/CU.
__global__ __launch_bounds__(256, 2)
void k_avproj(const unsigned short* __restrict__ dwoutB, const float* __restrict__ comb,
              const unsigned short* __restrict__ Pbf, float* __restrict__ out){
    __shared__ unsigned short Bl[128*200];  // [pos][K=192 + pad8] = g in bf16
    __shared__ float cm[6144];              // comb, all 6 heads
    int tid = threadIdx.x;
    int y2 = blockIdx.x, b = blockIdx.y;

    // stage comb (24 KB)
    #pragma unroll
    for (int j=0;j<24;j++) cm[tid + j*256] = comb[b*6144 + tid + j*256];

    // ---- phase 1: g[128 pos][192 ch] into Bl. 2 threads/pos (3 heads each). ----
    int n_loc = tid & 127, half = tid >> 7;
    const unsigned short* vb = dwoutB + (size_t)(b*576 + 384 + half*96)*NP + y2*128 + n_loc;
    __syncthreads();   // cm ready
    #pragma unroll 1
    for (int hh=0; hh<3; hh++){
        float v[32];
        #pragma unroll
        for (int d=0; d<32; d++) v[d] = bf2f(vb[(size_t)(hh*32+d)*NP]);
        const float* chp = &cm[(half*3+hh)*1024];
        #pragma unroll 1
        for (int cg=0; cg<4; cg++){
            float s[8];
            #pragma unroll
            for (int i=0;i<8;i++){
                const float* crow = chp + (cg*8+i)*32;
                float acc = 0.f;
                #pragma unroll
                for (int d=0;d<32;d++) acc += crow[d]*v[d];
                s[i] = 0.5f*acc*(1.f + erff(acc*0.70710678118654752f));
            }
            u32x4 pk;
            pk.x = pk2(s[0],s[1]); pk.y = pk2(s[2],s[3]);
            pk.z = pk2(s[4],s[5]); pk.w = pk2(s[6],s[7]);
            *(u32x4*)&Bl[n_loc*200 + half*96 + hh*32 + cg*8] = pk;
        }
    }

    // ---- phase 2: proj GEMM (verbatim k_proj) ----
    int lane = tid & 63, wv = tid >> 6;
    int n16 = lane & 15, quad = lane >> 4;
    bf16x8 afc[3], afn[3];
    #pragma unroll
    for (int j=0;j<3;j++)
        afc[j] = *(const bf16x8*)(Pbf + (size_t)(((wv*3+j)*16 + n16)*192 + quad*8));
    __syncthreads();   // Bl ready

    f32x4 acc[3][8];
    #pragma unroll
    for (int j=0;j<3;j++)
      #pragma unroll
      for (int s=0;s<8;s++)
        acc[j][s] = (f32x4){0.f,0.f,0.f,0.f};

    #pragma unroll 1
    for (int it=0; it<6; it++){
        if (it < 5){
            #pragma unroll
            for (int j=0;j<3;j++)
                afn[j] = *(const bf16x8*)(Pbf +
                    (size_t)(((wv*3+j)*16 + n16)*192 + (it+1)*32 + quad*8));
        }
        int bko = it*32 + quad*8;
        bf16x8 bfr[8];
        #pragma unroll
        for (int s=0;s<8;s++) bfr[s] = *(const bf16x8*)&Bl[(s*16 + n16)*200 + bko];
        #pragma unroll
        for (int j=0;j<3;j++)
          #pragma unroll
          for (int s=0;s<8;s++)
            acc[j][s] = __builtin_amdgcn_mfma_f32_16x16x32_bf16(afc[j], bfr[s], acc[j][s], 0,0,0);
        #pragma unroll
        for (int j=0;j<3;j++) afc[j] = afn[j];
    }

    #pragma unroll
    for (int j=0;j<3;j++){
        int oc = (wv*3+j)*16 + quad*4;
        #pragma unroll
        for (int sp=0;sp<8;sp++){
            int x2 = sp*16 + n16;
            #pragma unroll
            for (int r=0;r<4;r++){
                float v = acc[j][sp][r];
                size_t o = ((size_t)(b*192 + oc + r)*256 + 2*y2)*256 + 2*x2;
                float2 val = make_float2(v, v);
                *(float2*)(out + o) = val;
                *(float2*)(out + o + 256) = val;
            }
        }
    }
}

extern "C" void kernel_launch(void* const* d_in, const int* in_sizes, int n_in,
                              void* d_out, int out_size, void* d_ws, size_t ws_size,
                              hipStream_t stream){
    const float* x     = (const float*)d_in[0];
    const float* temp  = (const float*)d_in[1];
    const float* qkvw  = (const float*)d_in[2];
    const float* dww   = (const float*)d_in[3];
    const float* projw = (const float*)d_in[4];
    const float* A1    = (const float*)d_in[5];
    const float* A2    = (const float*)d_in[6];
    const float* A3    = (const float*)d_in[7];
    const float* A4    = (const float*)d_in[8];
    float* out = (float*)d_out;
    char* ws = (char*)d_ws;

    // workspace layout (bytes)
    unsigned short* dwoutB = (unsigned short*)ws;                    // 75,497,472
    unsigned short* qkvp   = (unsigned short*)(ws + 75497472ull);    // 75,497,472
    unsigned short* Wbf    = (unsigned short*)(ws + 150994944ull);   // 221,184
    unsigned short* Pbf    = (unsigned short*)(ws + 151216128ull);   // 73,728
    float*          attn   = (float*)(ws + 151289856ull);            // 98,304
    float*          comb   = (float*)(ws + 151388160ull);            // 98,304
    float*          sumsq  = (float*)(ws + 151486464ull);            // 6,144

    hipMemsetAsync(attn, 0, 98304, stream);
    hipMemsetAsync(sumsq, 0, 6144, stream);
    k_convert2<<<dim3((147456+255)/256), dim3(256), 0, stream>>>(qkvw, projw, Wbf, Pbf);
    k_qkvpool<<<dim3(512,4), dim3(256), 0, stream>>>(x, Wbf, qkvp);
    k_dwconv<<<dim3(8,576,4), dim3(256), 0, stream>>>(qkvp, dww, dwoutB, sumsq);
    k_attnraw<<<dim3(32,6,4), dim3(256), 0, stream>>>(dwoutB, attn);
    k_mask_softmax<<<dim3(24), dim3(1024), 0, stream>>>(attn, sumsq, temp, A1, A2, A3, A4, comb);
    k_avproj<<<dim3(128,4), dim3(256), 0, stream>>>(dwoutB, comb, Pbf, out);
}

// Round 7
// 522.028 us; speedup vs baseline: 1.1632x; 1.0466x over previous
//
#include <hip/hip_runtime.h>
#include <hip/hip_bf16.h>
#include <math.h>

typedef __attribute__((ext_vector_type(8))) short bf16x8;
typedef __attribute__((ext_vector_type(4))) float f32x4;
typedef __attribute__((ext_vector_type(4))) unsigned int u32x4;

#define NP 16384
#define HWFULL 65536

__device__ __forceinline__ unsigned short f2bf(float f){
    union { float f; unsigned int u; } v; v.f = f;
    unsigned int u = v.u;
    u += 0x7fffu + ((u >> 16) & 1u);
    return (unsigned short)(u >> 16);
}
__device__ __forceinline__ float bf2f(unsigned short h){
    union { unsigned int u; float f; } v; v.u = ((unsigned int)h) << 16;
    return v.f;
}
// HW packed bf16 convert (RNE, identical rounding to f2bf): 1 instr vs ~10
__device__ __forceinline__ unsigned int pk2(float a, float b){
    unsigned int r;
    asm("v_cvt_pk_bf16_f32 %0, %1, %2" : "=v"(r) : "v"(a), "v"(b));
    return r;
}

// ---- K0: fp32 -> bf16 weight conversion (qkv + proj in one launch) ----
__global__ void k_convert2(const float* __restrict__ qw, const float* __restrict__ pw,
                           unsigned short* __restrict__ Wbf, unsigned short* __restrict__ Pbf){
    int i = blockIdx.x * 256 + threadIdx.x;
    if (i < 110592) Wbf[i] = f2bf(qw[i]);
    else if (i < 110592 + 36864) Pbf[i - 110592] = f2bf(pw[i - 110592]);
}

// ---- K1: qkv 1x1 conv (bf16 MFMA GEMM) fused with 2x2 maxpool ----
// v4 structure (measured fixed point ~170us across 5 variants — do not retune).
// grid (512, 4): bx -> (y2 = bx>>2, x2blk = bx&3); by = b
__global__ __launch_bounds__(256, 2)
void k_qkvpool(const float* __restrict__ x, const unsigned short* __restrict__ Wbf,
               unsigned short* __restrict__ qkvp){
    __shared__ unsigned short Bl[128*200];  // [pos][K=192 + pad8] bf16, persistent
    __shared__ unsigned short Ep[192*36];   // pooled epilogue buffer
    int tid = threadIdx.x;
    int lane = tid & 63, wv = tid >> 6;
    int n16 = lane & 15, quad = lane >> 4;
    int bx = blockIdx.x;
    int y2 = bx >> 2, x2blk = bx & 3;
    int b = blockIdx.y;

    // ---- stage B: transpose-gather x[ic][pos] -> Bl[pos][ic], fp32->bf16, full K ----
    #pragma unroll 6
    for (int j=0;j<12;j++){
        int idx = tid + j*256;
        int g = idx >> 7, w = idx & 127;       // g: ic granule of 8; w: 0..63 row y, 64..127 row y+1
        int y = y2*2 + (w >> 6);
        int xc = x2blk*64 + (w & 63);
        const float* xp = x + (size_t)(b*192 + g*8) * HWFULL + y*256 + xc;
        float v0 = xp[0];
        float v1 = xp[(size_t)1*HWFULL];
        float v2 = xp[(size_t)2*HWFULL];
        float v3 = xp[(size_t)3*HWFULL];
        float v4 = xp[(size_t)4*HWFULL];
        float v5 = xp[(size_t)5*HWFULL];
        float v6 = xp[(size_t)6*HWFULL];
        float v7 = xp[(size_t)7*HWFULL];
        u32x4 pk;
        pk.x = pk2(v0,v1); pk.y = pk2(v2,v3); pk.z = pk2(v4,v5); pk.w = pk2(v6,v7);
        *(u32x4*)&Bl[w*200 + g*8] = pk;
    }
    // preload A fragments for (ocblk=0, it=0) — independent of LDS
    bf16x8 afc[3], afn[3];
    #pragma unroll
    for (int j=0;j<3;j++)
        afc[j] = *(const bf16x8*)(Wbf + (size_t)(((wv*3+j)*16 + n16)*192 + quad*8));
    __syncthreads();

    for (int ocblk=0; ocblk<3; ocblk++){
        f32x4 acc[3][8];
        #pragma unroll
        for (int j=0;j<3;j++)
          #pragma unroll
          for (int s=0;s<8;s++)
            acc[j][s] = (f32x4){0.f,0.f,0.f,0.f};

        #pragma unroll 1
        for (int it=0; it<6; it++){
            int nocb = (it==5) ? ocblk+1 : ocblk;
            int nit  = (it==5) ? 0 : it+1;
            if (nocb < 3){
                #pragma unroll
                for (int j=0;j<3;j++)
                    afn[j] = *(const bf16x8*)(Wbf +
                        (size_t)((nocb*192 + (wv*3+j)*16 + n16)*192 + nit*32 + quad*8));
            }
            int bko = it*32 + quad*8;
            bf16x8 bfr[8];
            #pragma unroll
            for (int s=0;s<8;s++) bfr[s] = *(const bf16x8*)&Bl[(s*16 + n16)*200 + bko];
            #pragma unroll
            for (int j=0;j<3;j++)
              #pragma unroll
              for (int s=0;s<8;s++)
                acc[j][s] = __builtin_amdgcn_mfma_f32_16x16x32_bf16(afc[j], bfr[s], acc[j][s], 0,0,0);
            #pragma unroll
            for (int j=0;j<3;j++) afc[j] = afn[j];
        }
        __syncthreads();   // prev ocblk's cooperative-store reads of Ep done
        // ---- epilogue: 2x2 maxpool into LDS (strip sp & sp+4 = rows y,y+1; lane^1 = x,x+1)
        #pragma unroll
        for (int j=0;j<3;j++){
            int ocr = (wv*3+j)*16 + quad*4;
            #pragma unroll
            for (int sp=0;sp<4;sp++){
                #pragma unroll
                for (int r=0;r<4;r++){
                    float v = fmaxf(acc[j][sp][r], acc[j][sp+4][r]);
                    float o = __shfl_xor(v, 1, 64);
                    v = fmaxf(v, o);
                    if ((n16 & 1) == 0)
                        Ep[(ocr + r)*36 + sp*8 + (n16 >> 1)] = f2bf(v);
                }
            }
        }
        __syncthreads();
        // ---- cooperative coalesced store: 192 rows x 32 shorts (64B/row) ----
        size_t rowbase = (size_t)(b*576 + ocblk*192)*NP + y2*128 + x2blk*32;
        #pragma unroll
        for (int it2=0; it2<6; it2++){
            int c = tid + it2*256;
            int row = c >> 3, seg = c & 7;
            uint2 vv = *(const uint2*)&Ep[row*36 + seg*4];
            *(uint2*)(qkvp + rowbase + (size_t)row*NP + seg*4) = vv;
        }
    }
}

// ---- K2: depthwise 3x3 SAME conv + per-channel sum-of-squares (q,k only) ----
// v4: ONE BLOCK PER CHANNEL IMAGE (2304 blocks vs 18432). Whole 32KB channel
// staged contiguously (no halo — borders are zeros, handled in regs); 64
// outputs/thread via rolling 3-row window. ssq: block reduce + direct store.
// grid (576, 4), block 256
__global__ __launch_bounds__(256) void k_dwconv(const unsigned short* __restrict__ qkvp,
                                                const float* __restrict__ dww,
                                                unsigned short* __restrict__ dwoutB,
                                                float* __restrict__ sumsq){
    __shared__ unsigned short sl[128*128];   // 32KB: whole channel image
    __shared__ float wr[4];
    int tid = threadIdx.x;
    int ch = blockIdx.x, b = blockIdx.y;
    const unsigned short* in = qkvp + (size_t)(b*576 + ch)*NP;
    #pragma unroll
    for (int j=0;j<8;j++){
        int idx = tid + j*256;
        *(u32x4*)&sl[idx*8] = *(const u32x4*)(in + idx*8);
    }
    float w0 = dww[ch*9+0], w1 = dww[ch*9+1], w2 = dww[ch*9+2];
    float w3 = dww[ch*9+3], w4 = dww[ch*9+4], w5 = dww[ch*9+5];
    float w6 = dww[ch*9+6], w7 = dww[ch*9+7], w8 = dww[ch*9+8];
    __syncthreads();
    int c = tid & 127, half = tid >> 7;     // half is wave-uniform (waves 0,1 / 2,3)
    float mL = (c > 0) ? 1.f : 0.f, mR = (c < 127) ? 1.f : 0.f;
    int cm = (c > 0) ? c-1 : c, cp = (c < 127) ? c+1 : c;
    unsigned short* outp = dwoutB + (size_t)(b*576 + ch)*NP;
    float ssq = 0.f;
    int r0 = half*64;
    float r0a, r0b, r0c, r1a, r1b, r1c;
    if (half == 0){ r0a = r0b = r0c = 0.f; }
    else { int rr = r0-1;
           r0a = bf2f(sl[rr*128+cm])*mL; r0b = bf2f(sl[rr*128+c]); r0c = bf2f(sl[rr*128+cp])*mR; }
    { int rr = r0;
      r1a = bf2f(sl[rr*128+cm])*mL; r1b = bf2f(sl[rr*128+c]); r1c = bf2f(sl[rr*128+cp])*mR; }
    #pragma unroll 4
    for (int i=0;i<64;i++){
        int rr = r0 + i + 1;
        float r2a, r2b, r2c;
        if (rr < 128){
            r2a = bf2f(sl[rr*128+cm])*mL; r2b = bf2f(sl[rr*128+c]); r2c = bf2f(sl[rr*128+cp])*mR;
        } else { r2a = r2b = r2c = 0.f; }
        float a = r0a*w0 + r0b*w1 + r0c*w2
                + r1a*w3 + r1b*w4 + r1c*w5
                + r2a*w6 + r2b*w7 + r2c*w8;
        outp[(r0+i)*128 + c] = (unsigned short)pk2(a, a);
        ssq += a*a;
        r0a=r1a; r0b=r1b; r0c=r1c;
        r1a=r2a; r1b=r2b; r1c=r2c;
    }
    if (ch < 384){
        #pragma unroll
        for (int off=32; off>0; off>>=1) ssq += __shfl_down(ssq, off, 64);
        if ((tid & 63) == 0) wr[tid >> 6] = ssq;
        __syncthreads();
        if (tid == 0) sumsq[b*384 + ch] = wr[0] + wr[1] + wr[2] + wr[3];
    }
}

// ---- K3a: raw attention gram matrix v5 — LDS-staged MFMA ----
// Stage q/k tiles [32][256] with fully-coalesced 512B-per-row global loads;
// fragments from LDS (fixes 16-way scattered 64B global loads of v3/v4).
// grid (64, 6, 4), block 256
__global__ __launch_bounds__(256) void k_attnraw(const unsigned short* __restrict__ dwoutB,
                                                 float* __restrict__ attn){
    __shared__ unsigned short sq[32*264];   // stride 264 shorts (16B-mult pad)
    __shared__ unsigned short sk[32*264];
    __shared__ float red[4][32][33];        // 16.9 KB
    int tid = threadIdx.x;
    int lane = tid & 63, wv = tid >> 6;
    int n16 = lane & 15, quad = lane >> 4;
    int h = blockIdx.y, b = blockIdx.z;
    int n0 = blockIdx.x * 256;
    const unsigned short* qb = dwoutB + (size_t)(b*576 + h*32)*NP + n0;
    const unsigned short* kb = dwoutB + (size_t)(b*576 + 192 + h*32)*NP + n0;

    #pragma unroll
    for (int j=0;j<4;j++){
        int idx = tid + j*256;           // 1024 loads per tensor
        int row = idx >> 5, seg = idx & 31;
        *(u32x4*)&sq[row*264 + seg*8] = *(const u32x4*)(qb + (size_t)row*NP + seg*8);
        *(u32x4*)&sk[row*264 + seg*8] = *(const u32x4*)(kb + (size_t)row*NP + seg*8);
    }
    __syncthreads();

    f32x4 acc[2][2];
    #pragma unroll
    for (int i=0;i<2;i++)
      #pragma unroll
      for (int j=0;j<2;j++) acc[i][j] = (f32x4){0.f,0.f,0.f,0.f};

    #pragma unroll
    for (int ks=0; ks<2; ks++){
        int ko = wv*64 + ks*32 + quad*8;
        bf16x8 aq0 = *(const bf16x8*)&sq[n16*264 + ko];
        bf16x8 aq1 = *(const bf16x8*)&sq[(16+n16)*264 + ko];
        bf16x8 bk0 = *(const bf16x8*)&sk[n16*264 + ko];
        bf16x8 bk1 = *(const bf16x8*)&sk[(16+n16)*264 + ko];
        acc[0][0] = __builtin_amdgcn_mfma_f32_16x16x32_bf16(aq0, bk0, acc[0][0], 0,0,0);
        acc[0][1] = __builtin_amdgcn_mfma_f32_16x16x32_bf16(aq0, bk1, acc[0][1], 0,0,0);
        acc[1][0] = __builtin_amdgcn_mfma_f32_16x16x32_bf16(aq1, bk0, acc[1][0], 0,0,0);
        acc[1][1] = __builtin_amdgcn_mfma_f32_16x16x32_bf16(aq1, bk1, acc[1][1], 0,0,0);
    }
    // C layout: row = cc*16 + quad*4 + r, col = dd*16 + n16
    #pragma unroll
    for (int cc=0; cc<2; cc++)
      #pragma unroll
      for (int dd=0; dd<2; dd++)
        #pragma unroll
        for (int r=0; r<4; r++)
          red[wv][cc*16 + quad*4 + r][dd*16 + n16] = acc[cc][dd][r];
    __syncthreads();
    float* ap = attn + (size_t)(b*6+h)*1024;
    #pragma unroll
    for (int j=0;j<4;j++){
        int o = tid + j*256;
        int c = o >> 5, d = o & 31;
        float v = red[0][c][d] + red[1][c][d] + red[2][c][d] + red[3][c][d];
        atomicAdd(ap + o, v);
    }
}

// ---- K3b: normalize, temperature, 4x top-k masked softmax, combine ----
// grid 24, block 1024
__global__ void k_mask_softmax(const float* __restrict__ attn, const float* __restrict__ sumsq,
                               const float* __restrict__ temp,
                               const float* __restrict__ A1, const float* __restrict__ A2,
                               const float* __restrict__ A3, const float* __restrict__ A4,
                               float* __restrict__ comb){
    __shared__ float Am[32][33];
    __shared__ float qn[32], kn[32];
    int t = threadIdx.x;
    int bh = blockIdx.x;
    int b = bh / 6, h = bh % 6;
    if (t < 32) qn[t] = fmaxf(sqrtf(sumsq[b*384 + h*32 + t]), 1e-12f);
    else if (t >= 64 && t < 96) kn[t-64] = fmaxf(sqrtf(sumsq[b*384 + 192 + h*32 + (t-64)]), 1e-12f);
    __syncthreads();
    int c = t >> 5, d = t & 31;
    float tv = temp[h];
    float am = attn[(size_t)bh*1024 + t] * tv / (qn[c]*kn[d]);
    Am[c][d] = am;
    // row max (32-lane subgroups)
    float m = am;
    #pragma unroll
    for (int off=16; off>0; off>>=1) m = fmaxf(m, __shfl_down(m, off, 32));
    m = __shfl(m, 0, 32);
    float e = expf(am - m);
    __syncthreads();
    // exact rank (ties broken by index, matching top_k semantics)
    int rk = 0;
    #pragma unroll 8
    for (int dd=0; dd<32; dd++){
        float av = Am[c][dd];
        rk += (av > am) || (av == am && dd < d);
    }
    float e0 = rk < 16 ? e : 0.f;
    float e1 = rk < 21 ? e : 0.f;
    float e2 = rk < 24 ? e : 0.f;
    float e3 = rk < 25 ? e : 0.f;
    #pragma unroll
    for (int off=16; off>0; off>>=1){
        e0 += __shfl_down(e0, off, 32);
        e1 += __shfl_down(e1, off, 32);
        e2 += __shfl_down(e2, off, 32);
        e3 += __shfl_down(e3, off, 32);
    }
    float d0 = __shfl(e0, 0, 32), d1 = __shfl(e1, 0, 32);
    float d2 = __shfl(e2, 0, 32), d3 = __shfl(e3, 0, 32);
    float s = (rk<16 ? A1[0]/d0 : 0.f) + (rk<21 ? A2[0]/d1 : 0.f)
            + (rk<24 ? A3[0]/d2 : 0.f) + (rk<25 ? A4[0]/d3 : 0.f);
    comb[(size_t)bh*1024 + t] = e * s;
}

// ---- K4: FUSED applyv + proj: g = gelu(comb @ v) built in LDS (bf16), then
// proj GEMM + nearest-2x upsample. grid (128, 4), block 256. 2 blocks/CU.
__global__ __launch_bounds__(256, 2)
void k_avproj(const unsigned short* __restrict__ dwoutB, const float* __restrict__ comb,
              const unsigned short* __restrict__ Pbf, float* __restrict__ out){
    __shared__ unsigned short Bl[128*200];  // [pos][K=192 + pad8] = g in bf16
    __shared__ float cm[6144];              // comb, all 6 heads
    int tid = threadIdx.x;
    int y2 = blockIdx.x, b = blockIdx.y;

    // stage comb (24 KB)
    #pragma unroll
    for (int j=0;j<24;j++) cm[tid + j*256] = comb[b*6144 + tid + j*256];

    // ---- phase 1: g[128 pos][192 ch] into Bl. 2 threads/pos (3 heads each). ----
    int n_loc = tid & 127, half = tid >> 7;
    const unsigned short* vb = dwoutB + (size_t)(b*576 + 384 + half*96)*NP + y2*128 + n_loc;
    __syncthreads();   // cm ready
    #pragma unroll 1
    for (int hh=0; hh<3; hh++){
        float v[32];
        #pragma unroll
        for (int d=0; d<32; d++) v[d] = bf2f(vb[(size_t)(hh*32+d)*NP]);
        const float* chp = &cm[(half*3+hh)*1024];
        #pragma unroll 1
        for (int cg=0; cg<4; cg++){
            float s[8];
            #pragma unroll
            for (int i=0;i<8;i++){
                const float* crow = chp + (cg*8+i)*32;
                float acc = 0.f;
                #pragma unroll
                for (int d=0;d<32;d++) acc += crow[d]*v[d];
                s[i] = 0.5f*acc*(1.f + erff(acc*0.70710678118654752f));
            }
            u32x4 pk;
            pk.x = pk2(s[0],s[1]); pk.y = pk2(s[2],s[3]);
            pk.z = pk2(s[4],s[5]); pk.w = pk2(s[6],s[7]);
            *(u32x4*)&Bl[n_loc*200 + half*96 + hh*32 + cg*8] = pk;
        }
    }

    // ---- phase 2: proj GEMM (verbatim k_proj) ----
    int lane = tid & 63, wv = tid >> 6;
    int n16 = lane & 15, quad = lane >> 4;
    bf16x8 afc[3], afn[3];
    #pragma unroll
    for (int j=0;j<3;j++)
        afc[j] = *(const bf16x8*)(Pbf + (size_t)(((wv*3+j)*16 + n16)*192 + quad*8));
    __syncthreads();   // Bl ready

    f32x4 acc[3][8];
    #pragma unroll
    for (int j=0;j<3;j++)
      #pragma unroll
      for (int s=0;s<8;s++)
        acc[j][s] = (f32x4){0.f,0.f,0.f,0.f};

    #pragma unroll 1
    for (int it=0; it<6; it++){
        if (it < 5){
            #pragma unroll
            for (int j=0;j<3;j++)
                afn[j] = *(const bf16x8*)(Pbf +
                    (size_t)(((wv*3+j)*16 + n16)*192 + (it+1)*32 + quad*8));
        }
        int bko = it*32 + quad*8;
        bf16x8 bfr[8];
        #pragma unroll
        for (int s=0;s<8;s++) bfr[s] = *(const bf16x8*)&Bl[(s*16 + n16)*200 + bko];
        #pragma unroll
        for (int j=0;j<3;j++)
          #pragma unroll
          for (int s=0;s<8;s++)
            acc[j][s] = __builtin_amdgcn_mfma_f32_16x16x32_bf16(afc[j], bfr[s], acc[j][s], 0,0,0);
        #pragma unroll
        for (int j=0;j<3;j++) afc[j] = afn[j];
    }

    #pragma unroll
    for (int j=0;j<3;j++){
        int oc = (wv*3+j)*16 + quad*4;
        #pragma unroll
        for (int sp=0;sp<8;sp++){
            int x2 = sp*16 + n16;
            #pragma unroll
            for (int r=0;r<4;r++){
                float v = acc[j][sp][r];
                size_t o = ((size_t)(b*192 + oc + r)*256 + 2*y2)*256 + 2*x2;
                float2 val = make_float2(v, v);
                *(float2*)(out + o) = val;
                *(float2*)(out + o + 256) = val;
            }
        }
    }
}

extern "C" void kernel_launch(void* const* d_in, const int* in_sizes, int n_in,
                              void* d_out, int out_size, void* d_ws, size_t ws_size,
                              hipStream_t stream){
    const float* x     = (const float*)d_in[0];
    const float* temp  = (const float*)d_in[1];
    const float* qkvw  = (const float*)d_in[2];
    const float* dww   = (const float*)d_in[3];
    const float* projw = (const float*)d_in[4];
    const float* A1    = (const float*)d_in[5];
    const float* A2    = (const float*)d_in[6];
    const float* A3    = (const float*)d_in[7];
    const float* A4    = (const float*)d_in[8];
    float* out = (float*)d_out;
    char* ws = (char*)d_ws;

    // workspace layout (bytes)
    unsigned short* dwoutB = (unsigned short*)ws;                    // 75,497,472
    unsigned short* qkvp   = (unsigned short*)(ws + 75497472ull);    // 75,497,472
    unsigned short* Wbf    = (unsigned short*)(ws + 150994944ull);   // 221,184
    unsigned short* Pbf    = (unsigned short*)(ws + 151216128ull);   // 73,728
    float*          attn   = (float*)(ws + 151289856ull);            // 98,304
    float*          comb   = (float*)(ws + 151388160ull);            // 98,304
    float*          sumsq  = (float*)(ws + 151486464ull);            // 6,144

    hipMemsetAsync(attn, 0, 98304, stream);
    k_convert2<<<dim3((147456+255)/256), dim3(256), 0, stream>>>(qkvw, projw, Wbf, Pbf);
    k_qkvpool<<<dim3(512,4), dim3(256), 0, stream>>>(x, Wbf, qkvp);
    k_dwconv<<<dim3(576,4), dim3(256), 0, stream>>>(qkvp, dww, dwoutB, sumsq);
    k_attnraw<<<dim3(64,6,4), dim3(256), 0, stream>>>(dwoutB, attn);
    k_mask_softmax<<<dim3(24), dim3(1024), 0, stream>>>(attn, sumsq, temp, A1, A2, A3, A4, comb);
    k_avproj<<<dim3(128,4), dim3(256), 0, stream>>>(dwoutB, comb, Pbf, out);
}